// Round 8
// baseline (76.479 us; speedup 1.0000x reference)
//
#include <hip/hip_runtime.h>
#include <hip/hip_fp16.h>

#define MB   2048   // model batches
#define NP   8192   // num points (scan length)
#define NF   8      // number of functions
#define RM   51     // removed leading iterations
#define NCH  128    // chunks per batch
#define CH   64     // NP / NCH, steps per chunk
#define NW   16     // packed code words per chunk (CH/4)

typedef float        f32x4 __attribute__((ext_vector_type(4)));
typedef unsigned int u32;

// ws: mapsA float4[NCH*MB] @0 (4MB) | mapsC float2[NCH*MB] @4MB (2MB)
//     pe float2[NCH*MB] @6MB (2MB)  | codes u32[NCH*NW*MB] @8MB (16MB)

// f16 table: one uint4 per function = {h2(w00,w01), h2(w10,w11), h2(b0,b1), h2(op,0)}
// 8 entries x 16B -> b128 reads hit 8 distinct bank-quads: conflict-free broadcast.
__device__ __forceinline__ void build_tbl(u32 (*tbl)[4], const float* W,
                                          const float* B, const float* OPS, int tid)
{
    if (tid < NF) {
        const __half2 h0 = __floats2half2_rn(W[tid*4+0], W[tid*4+1]);
        const __half2 h1 = __floats2half2_rn(W[tid*4+2], W[tid*4+3]);
        const __half2 h2 = __floats2half2_rn(B[tid*2+0], B[tid*2+1]);
        const __half2 h3 = __floats2half2_rn(OPS ? OPS[tid] : 0.f, 0.f);
        tbl[tid][0] = __builtin_bit_cast(u32, h0);
        tbl[tid][1] = __builtin_bit_cast(u32, h1);
        tbl[tid][2] = __builtin_bit_cast(u32, h2);
        tbl[tid][3] = __builtin_bit_cast(u32, h3);
    }
}

// ---------------- Phase 1: compose 64-step chunk maps + emit packed codes ----------------
__global__ __launch_bounds__(256, 4) void ifs_phase1(
    const int* __restrict__ idxg, const float* __restrict__ W,
    const float* __restrict__ B,
    float4* __restrict__ mapsA, float2* __restrict__ mapsC, u32* __restrict__ codes)
{
    __shared__ u32 ptile[256][NW + 1];          // 17.4 KB; reads (17t+w)%32 = 2-way free
    __shared__ __align__(16) u32 tbl[NF][4];
    const int tid = threadIdx.x;
    build_tbl(tbl, W, B, nullptr, tid);

    const int c  = blockIdx.x >> 3;
    const int b0 = (blockIdx.x & 7) << 8;
    const int x8 = tid & 7, yy = tid >> 3;

    auto stage = [&](int seg) {                 // 8 lanes x int4 = 128B/row: coalesced
        #pragma unroll
        for (int p = 0; p < 8; ++p) {
            const int row = yy + p * 32;
            const int4 v = *(const int4*)(idxg + (size_t)(b0 + row) * NP
                                          + c * CH + seg * 32 + x8 * 4);
            ptile[row][seg * 8 + x8] =
                (u32)v.x | ((u32)v.y << 8) | ((u32)v.z << 16) | ((u32)v.w << 24);
        }
    };
    stage(0);
    __syncthreads();                            // stage(0) + tbl visible

    float a00 = 1.f, a01 = 0.f, a10 = 0.f, a11 = 1.f, c0 = 0.f, c1 = 0.f;
    for (int seg = 0; seg < 2; ++seg) {
        if (seg == 0) stage(1);                 // overlap fetch with compose
        #pragma unroll
        for (int j = 0; j < 8; ++j) {
            const u32 pc = ptile[tid][seg * 8 + j];
            #pragma unroll
            for (int e = 0; e < 4; ++e) {
                const int f = (pc >> (8 * e)) & 7;
                const uint4 u = *(const uint4*)&tbl[f][0];   // ONE b128 per step
                const float2 w0 = __half22float2(__builtin_bit_cast(__half2, u.x));
                const float2 w1 = __half22float2(__builtin_bit_cast(__half2, u.y));
                const float2 bb = __half22float2(__builtin_bit_cast(__half2, u.z));
                const float na00 = w0.x*a00 + w0.y*a10;
                const float na01 = w0.x*a01 + w0.y*a11;
                const float na10 = w1.x*a00 + w1.y*a10;
                const float na11 = w1.x*a01 + w1.y*a11;
                const float nc0  = w0.x*c0  + w0.y*c1 + bb.x;
                const float nc1  = w1.x*c0  + w1.y*c1 + bb.y;
                a00 = na00; a01 = na01; a10 = na10; a11 = na11; c0 = nc0; c1 = nc1;
            }
        }
        __syncthreads();                        // publish stage(1) / guard reads
    }
    // writeback packed codes: per w, lanes -> consecutive b: coalesced b32 stores
    #pragma unroll
    for (int w = 0; w < NW; ++w)
        codes[((size_t)c * NW + w) * MB + b0 + tid] = ptile[tid][w];
    mapsA[(size_t)c * MB + b0 + tid] = make_float4(a00, a01, a10, a11);
    mapsC[(size_t)c * MB + b0 + tid] = make_float2(c0, c1);
}

// ---------------- Phase 2: sequential scan over 128 chunk maps (8-deep prefetch) ----------------
__global__ __launch_bounds__(64) void ifs_phase2(
    const float2* __restrict__ point, const float4* __restrict__ mapsA,
    const float2* __restrict__ mapsC, float2* __restrict__ pe)
{
    const int b = blockIdx.x * 64 + threadIdx.x;   // 32 blocks -> 32 CUs
    float2 p = point[b];
    float4 A0[8], A1[8]; float2 C0[8], C1[8];
    #pragma unroll
    for (int k = 0; k < 8; ++k) {
        A0[k] = mapsA[(size_t)k * MB + b];
        C0[k] = mapsC[(size_t)k * MB + b];
    }
    for (int g = 0; g < 16; ++g) {
        if (g < 15) {
            #pragma unroll
            for (int k = 0; k < 8; ++k) {
                A1[k] = mapsA[(size_t)((g + 1) * 8 + k) * MB + b];
                C1[k] = mapsC[(size_t)((g + 1) * 8 + k) * MB + b];
            }
        }
        #pragma unroll
        for (int k = 0; k < 8; ++k) {
            pe[(size_t)(g * 8 + k) * MB + b] = p;
            const float nx = A0[k].x * p.x + A0[k].y * p.y + C0[k].x;
            const float ny = A0[k].z * p.x + A0[k].w * p.y + C0[k].y;
            p.x = nx; p.y = ny;
        }
        #pragma unroll
        for (int k = 0; k < 8; ++k) { A0[k] = A1[k]; C0[k] = C1[k]; }
    }
}

// ---------------- Phase 3: replay from packed codes, transpose-coalesced out ----------------
__global__ __launch_bounds__(256, 4) void ifs_phase3(
    const u32* __restrict__ codes, const float* __restrict__ W,
    const float* __restrict__ B, const float* __restrict__ OPS,
    const float2* __restrict__ pe, float* __restrict__ out)
{
    __shared__ __align__(16) float sbuf[2][4][256][3];  // ping-pong transpose (24 KB)
    __shared__ __align__(16) u32 tbl[NF][4];
    const int tid = threadIdx.x;
    build_tbl(tbl, W, B, OPS, tid);

    const int c  = blockIdx.x >> 3;
    const int b0 = (blockIdx.x & 7) << 8;
    const int b  = b0 + tid;

    // all code words + entry state up front: coalesced, latency hidden by setup
    u32 code[NW];
    #pragma unroll
    for (int w = 0; w < NW; ++w)
        code[w] = codes[((size_t)c * NW + w) * MB + b];
    const float2 p0 = pe[(size_t)c * MB + b];

    // store-side decomposition: f32x4 k covers flat words w=4*(tid+256k) of the
    // 4x256x3-word group tile; step s=w/768, col r=w%768
    int s_[3];
    long long off[3];
    #pragma unroll
    for (int k = 0; k < 3; ++k) {
        const int w = 4 * (tid + 256 * k);
        s_[k] = w / 768;
        const int r = w - s_[k] * 768;
        off[k] = (long long)(c * CH + s_[k] - RM) * (MB * 3) + b0 * 3 + r;
    }
    const bool chk = (c == 0);
    float2 p = p0;
    __syncthreads();                            // tbl visible

    for (int g = 0; g < 16; ++g) {              // 16 groups x 4 steps
        const int buf = g & 1;
        const u32 pc = code[g];
        #pragma unroll
        for (int s = 0; s < 4; ++s) {
            const int f = (pc >> (8 * s)) & 7;
            const uint4 u = *(const uint4*)&tbl[f][0];       // ONE b128
            const float2 w0 = __half22float2(__builtin_bit_cast(__half2, u.x));
            const float2 w1 = __half22float2(__builtin_bit_cast(__half2, u.y));
            const float2 bb = __half22float2(__builtin_bit_cast(__half2, u.z));
            const float op  = __low2float(__builtin_bit_cast(__half2, u.w));
            const float nx = w0.x * p.x + w0.y * p.y + bb.x;
            const float ny = w1.x * p.x + w1.y * p.y + bb.y;
            p.x = nx; p.y = ny;
            sbuf[buf][s][tid][0] = nx;          // stride-3 b32: 2-way = free
            sbuf[buf][s][tid][1] = ny;
            sbuf[buf][s][tid][2] = op;
        }
        __syncthreads();                        // one barrier per group (ping-pong)
        const float* flat = &sbuf[buf][0][0][0];
        #pragma unroll
        for (int k = 0; k < 3; ++k) {
            if (!chk || (g * 4 + s_[k]) >= RM) {
                const f32x4 v = *(const f32x4*)(flat + 4 * (tid + 256 * k));
                __builtin_nontemporal_store(v, (f32x4*)(out + off[k]));
            }
            off[k] += 4LL * (MB * 3);
        }
    }
}

extern "C" void kernel_launch(void* const* d_in, const int* in_sizes, int n_in,
                              void* d_out, int out_size, void* d_ws, size_t ws_size,
                              hipStream_t stream) {
    const float* point = (const float*)d_in[0];  // [2048,2,1]
    const float* W     = (const float*)d_in[1];  // [8,2,2]
    const float* B     = (const float*)d_in[2];  // [8,2,1]
    const float* OPS   = (const float*)d_in[3];  // [8]
    const int*   idx   = (const int*)  d_in[4];  // [2048,8192]
    float*       out   = (float*)d_out;          // [(8192-51)*2048, 3]

    char* ws = (char*)d_ws;
    float4* mapsA = (float4*)(ws);                                 // 4 MB
    float2* mapsC = (float2*)(ws + (size_t)NCH * MB * 16);         // 2 MB
    float2* pe    = (float2*)(ws + (size_t)NCH * MB * 24);         // 2 MB
    u32*    codes = (u32*)   (ws + (size_t)NCH * MB * 32);         // 16 MB

    ifs_phase1<<<NCH * (MB / 256), 256, 0, stream>>>(idx, W, B, mapsA, mapsC, codes);
    ifs_phase2<<<MB / 64, 64, 0, stream>>>((const float2*)point, mapsA, mapsC, pe);
    ifs_phase3<<<NCH * (MB / 256), 256, 0, stream>>>(codes, W, B, OPS, pe, out);
}